// Round 20
// baseline (527.970 us; speedup 1.0000x reference)
//
#include <hip/hip_runtime.h>

#define N_NODES 20000
#define N_EDGES 320000
#define HD 256
#define NLAYERS 7
#define NGRAPH 512
#define NOUT 128
#define NTILES 625   // 20000 / 32
#define SP_BLOCKS 1024

typedef __attribute__((ext_vector_type(8))) short bf16x8;
typedef __attribute__((ext_vector_type(4))) int i32x4;
typedef __attribute__((ext_vector_type(4))) float f32x4;

__device__ __forceinline__ ushort f2bf(float f) {
    union { float f; unsigned u; } v;
    v.f = f;
    unsigned r = (v.u + 0x7FFFu + ((v.u >> 16) & 1u)) >> 16;
    return (ushort)r;
}
__device__ __forceinline__ float bf2f(ushort u) {
    union { unsigned u; float f; } v;
    v.u = (unsigned)u << 16;
    return v.f;
}
__device__ __forceinline__ float bflo(unsigned p) {
    union { unsigned u; float f; } v;
    v.u = p << 16;
    return v.f;
}
__device__ __forceinline__ float bfhi(unsigned p) {
    union { unsigned u; float f; } v;
    v.u = p & 0xffff0000u;
    return v.f;
}

// ---------------- CSR build ----------------
__global__ __launch_bounds__(256) void hist_kernel(const int* __restrict__ dst, int* __restrict__ hist) {
    int e = blockIdx.x * 256 + threadIdx.x;
    if (e < N_EDGES) atomicAdd(&hist[dst[e]], 1);
}

__global__ __launch_bounds__(1024) void scan_kernel(const int* __restrict__ hist,
                                                    int* __restrict__ row_ptr,
                                                    int* __restrict__ cursor) {
    __shared__ int sums[1024];
    int t = threadIdx.x;
    const int CH = 20;
    int base = t * CH;
    int local[20];
    int s = 0;
#pragma unroll
    for (int i = 0; i < CH; i++) {
        int v = (base + i < N_NODES) ? hist[base + i] : 0;
        local[i] = s;
        s += v;
    }
    sums[t] = s;
    __syncthreads();
    for (int off = 1; off < 1024; off <<= 1) {
        int v = (t >= off) ? sums[t - off] : 0;
        __syncthreads();
        sums[t] += v;
        __syncthreads();
    }
    int offset = (t == 0) ? 0 : sums[t - 1];
#pragma unroll
    for (int i = 0; i < CH; i++) {
        int idx = base + i;
        if (idx < N_NODES) {
            int v = offset + local[i];
            row_ptr[idx] = v;
            cursor[idx] = v;
        }
    }
    if (t == 1023) row_ptr[N_NODES] = sums[1023];
}

// pack = src | (combo << 15)   (src < 32768, combo < 125)
__global__ __launch_bounds__(256) void scatter_kernel(const int* __restrict__ dst,
                                                      const int* __restrict__ src,
                                                      const int* __restrict__ ef,
                                                      int* __restrict__ cursor,
                                                      unsigned* __restrict__ pack_sorted) {
    int e = blockIdx.x * 256 + threadIdx.x;
    if (e < N_EDGES) {
        int d = dst[e];
        int p = atomicAdd(&cursor[d], 1);
        unsigned cb = (unsigned)(ef[e * 3] * 25 + ef[e * 3 + 1] * 5 + ef[e * 3 + 2]);
        pack_sorted[p] = (unsigned)src[e] | (cb << 15);
    }
}

// ---------------- bond-embedding combo tables (bf16): [L][125][H] ----------------
__global__ __launch_bounds__(256) void hetab_kernel(const float* __restrict__ bond,
                                                    ushort* __restrict__ he) {
    int idx = blockIdx.x * 256 + threadIdx.x;
    if (idx >= NLAYERS * 125 * HD) return;
    int h = idx & (HD - 1);
    int rem = idx >> 8;
    int l = rem / 125;
    int c = rem - l * 125;
    int f0 = c / 25, f1 = (c / 5) % 5, f2 = c % 5;
    const float* b = bond + (size_t)l * 3 * 8 * HD;
    he[idx] = f2bf(b[(0 * 8 + f0) * HD + h] + b[(1 * 8 + f1) * HD + h] + b[(2 * 8 + f2) * HD + h]);
}

// ---- W -> Wt2 bf16, k-slice-major: Wt2[l][ks][n][kg][8], ks=k>>5, kg=(k>>3)&3, j=k&7 ----
__global__ __launch_bounds__(256) void wt_kernel(const float* __restrict__ W,
                                                 ushort* __restrict__ Wt) {
    int b = blockIdx.x;
    int l = b >> 8;
    int n = b & 255;
    int k = threadIdx.x;
    float v = W[((size_t)l * HD + k) * HD + n];
    int ks = k >> 5, kg = (k >> 3) & 3, j = k & 7;
    Wt[(((size_t)l * 8 + ks) * 256 + n) * 32 + kg * 8 + j] = f2bf(v);
}

// ------- atom encoder: 8 nodes/block, NO atomics (stats decoupled) ----------
__global__ __launch_bounds__(256) void atom_kernel(const int* __restrict__ nf,
                                                   const float* __restrict__ emb,
                                                   float* __restrict__ hv) {
    int c = threadIdx.x;
    int n0 = blockIdx.x * 8;
#pragma unroll
    for (int i = 0; i < 8; i++) {
        int n = n0 + i;
        const int* f = nf + n * 9;
        float v = 0.f;
#pragma unroll
        for (int j = 0; j < 9; j++) v += emb[(j * 128 + f[j]) * HD + c];
        hv[(size_t)n * HD + c] = v;
    }
}

// ------- layer-0 BN stat partials: 1024 blocks, NO atomics ----------
__global__ __launch_bounds__(256) void statsp_kernel(const float* __restrict__ hv,
                                                     float* __restrict__ part) {
    int c = threadIdx.x;
    float s1 = 0.f, s2 = 0.f;
    for (int n = blockIdx.x; n < N_NODES; n += SP_BLOCKS) {
        float v = hv[(size_t)n * HD + c];
        s1 += v;
        s2 += v * v;
    }
    float* dst = part + (size_t)blockIdx.x * 512;
    dst[c] = s1;
    dst[256 + c] = s2;
}

// ------- reduce per-block partials -> stats (spread atomics) ----------
__global__ __launch_bounds__(256) void statsred_kernel(const float* __restrict__ part,
                                                       float* __restrict__ stats,
                                                       int nblocks) {
    int c = threadIdx.x;
    float a0 = 0.f, a1 = 0.f;
    for (int b = blockIdx.x; b < nblocks; b += gridDim.x) {
        a0 += part[(size_t)b * 512 + c];
        a1 += part[(size_t)b * 512 + 256 + c];
    }
    atomicAdd(&stats[c], a0);
    atomicAdd(&stats[HD + c], a1);
}

// ---------------- BN+ReLU -> bf16 h1 ----------------
__global__ __launch_bounds__(256) void bn_kernel(const float* __restrict__ hv,
                                                 const float* __restrict__ stats,
                                                 const float* __restrict__ gamma,
                                                 const float* __restrict__ beta,
                                                 ushort* __restrict__ h1) {
    int tid = blockIdx.x * 256 + threadIdx.x;  // N*HD/8 threads
    int idx = tid * 8;
    int c = idx & (HD - 1);
    float4 f0 = *reinterpret_cast<const float4*>(hv + idx);
    float4 f1 = *reinterpret_cast<const float4*>(hv + idx + 4);
    float v[8] = {f0.x, f0.y, f0.z, f0.w, f1.x, f1.y, f1.z, f1.w};
    ushort o[8];
#pragma unroll
    for (int j = 0; j < 8; j++) {
        float mu = stats[c + j] * (1.0f / N_NODES);
        float var = stats[HD + c + j] * (1.0f / N_NODES) - mu * mu;
        float a = gamma[c + j] * rsqrtf(fmaxf(var, 0.f) + 1e-5f);
        float b = beta[c + j] - mu * a;
        o[j] = f2bf(fmaxf(fmaf(v[j], a, b), 0.f));
    }
    i32x4 pack;
    pack.x = (int)o[0] | ((int)o[1] << 16);
    pack.y = (int)o[2] | ((int)o[3] << 16);
    pack.z = (int)o[4] | ((int)o[5] << 16);
    pack.w = (int)o[6] | ((int)o[7] << 16);
    *reinterpret_cast<i32x4*>(h1 + idx) = pack;
}

// ---- edge pass: wave/node, 4ch/lane, 64-edge preload, 8-deep gather pipeline ----
__global__ __launch_bounds__(256) void edge_kernel(const ushort* __restrict__ h1,
                                                   ushort* __restrict__ xbf,
                                                   const int* __restrict__ row_ptr,
                                                   const unsigned* __restrict__ pack_sorted,
                                                   const ushort* __restrict__ hetab) {
    int wv = threadIdx.x >> 6;
    int lane = threadIdx.x & 63;
    int n = blockIdx.x * 4 + wv;
    int c4 = lane * 4;
    int e0 = row_ptr[n];
    int deg = row_ptr[n + 1] - e0;

    float S0 = 0.f, S1 = 0.f, S2 = 0.f, S3 = 0.f;
    float T0 = 0.f, T1 = 0.f, T2 = 0.f, T3 = 0.f;

#define GATHER(i, P)                                                                          \
    uint2 hs##i = *reinterpret_cast<const uint2*>(h1 + ((size_t)((P) & 0x7FFFu) << 8) + c4);  \
    uint2 hb##i = *reinterpret_cast<const uint2*>(hetab + (((P) >> 15) << 8) + c4);

#define EDGE_PROC(HS, HB)                                                  \
    {                                                                      \
        float m0 = fmaxf(bflo(HS.x) + bflo(HB.x), 0.f);                    \
        float m1 = fmaxf(bfhi(HS.x) + bfhi(HB.x), 0.f);                    \
        float m2 = fmaxf(bflo(HS.y) + bflo(HB.y), 0.f);                    \
        float m3 = fmaxf(bfhi(HS.y) + bfhi(HB.y), 0.f);                    \
        float x0 = __expf(m0), x1 = __expf(m1), x2 = __expf(m2), x3 = __expf(m3); \
        S0 += x0; T0 = fmaf(m0, x0, T0);                                   \
        S1 += x1; T1 = fmaf(m1, x1, T1);                                   \
        S2 += x2; T2 = fmaf(m2, x2, T2);                                   \
        S3 += x3; T3 = fmaf(m3, x3, T3);                                   \
    }

    for (int base = 0; base < deg; base += 64) {
        int cnt = min(64, deg - base);
        unsigned pk = (lane < cnt) ? pack_sorted[e0 + base + lane] : 0u;
        int j = 0;
        for (; j + 8 <= cnt; j += 8) {
            unsigned p0 = __shfl(pk, j + 0);
            unsigned p1 = __shfl(pk, j + 1);
            unsigned p2 = __shfl(pk, j + 2);
            unsigned p3 = __shfl(pk, j + 3);
            unsigned p4 = __shfl(pk, j + 4);
            unsigned p5 = __shfl(pk, j + 5);
            unsigned p6 = __shfl(pk, j + 6);
            unsigned p7 = __shfl(pk, j + 7);
            GATHER(0, p0) GATHER(1, p1) GATHER(2, p2) GATHER(3, p3)
            GATHER(4, p4) GATHER(5, p5) GATHER(6, p6) GATHER(7, p7)
            EDGE_PROC(hs0, hb0) EDGE_PROC(hs1, hb1) EDGE_PROC(hs2, hb2) EDGE_PROC(hs3, hb3)
            EDGE_PROC(hs4, hb4) EDGE_PROC(hs5, hb5) EDGE_PROC(hs6, hb6) EDGE_PROC(hs7, hb7)
        }
        for (; j + 4 <= cnt; j += 4) {
            unsigned p0 = __shfl(pk, j + 0);
            unsigned p1 = __shfl(pk, j + 1);
            unsigned p2 = __shfl(pk, j + 2);
            unsigned p3 = __shfl(pk, j + 3);
            GATHER(0, p0) GATHER(1, p1) GATHER(2, p2) GATHER(3, p3)
            EDGE_PROC(hs0, hb0) EDGE_PROC(hs1, hb1) EDGE_PROC(hs2, hb2) EDGE_PROC(hs3, hb3)
        }
        for (; j < cnt; j++) {
            unsigned p0 = __shfl(pk, j);
            GATHER(0, p0)
            EDGE_PROC(hs0, hb0)
        }
    }
#undef EDGE_PROC
#undef GATHER

    // softmax weights shift-invariant in the +1e-7; m linear in it -> add at end
    float a0 = (S0 > 0.f) ? (T0 / S0 + 1e-7f) : 0.f;
    float a1 = (S1 > 0.f) ? (T1 / S1 + 1e-7f) : 0.f;
    float a2 = (S2 > 0.f) ? (T2 / S2 + 1e-7f) : 0.f;
    float a3 = (S3 > 0.f) ? (T3 / S3 + 1e-7f) : 0.f;

    uint2 ho = *reinterpret_cast<const uint2*>(h1 + ((size_t)n << 8) + c4);
    unsigned o0 = f2bf(bflo(ho.x) + a0);
    unsigned o1 = f2bf(bfhi(ho.x) + a1);
    unsigned o2 = f2bf(bflo(ho.y) + a2);
    unsigned o3 = f2bf(bfhi(ho.y) + a3);
    uint2 res;
    res.x = o0 | (o1 << 16);
    res.y = o2 | (o3 << 16);
    *reinterpret_cast<uint2*>(xbf + ((size_t)n << 8) + c4) = res;
}

// ------- MFMA MLP, persistent tiles: W in regs; residual prefetched; partials, no atomics --
__global__ __launch_bounds__(256, 2) void mlp_mfma_kernel(const ushort* __restrict__ xbf,
                                                          float* __restrict__ hv,
                                                          const ushort* __restrict__ Wt,
                                                          const float* __restrict__ bias,
                                                          float* __restrict__ part,
                                                          int accum_stats) {
    __shared__ __attribute__((aligned(16))) ushort xs[32 * 256];  // bf16, XOR-swizzled 16B units

    int t = threadIdx.x;
    int l = t & 63;
    int w = t >> 6;
    int kg = l >> 4;         // k-group 0..3
    int lr = l & 15;         // row (A) / col (B/D) within tile

    // --- load this wave's W columns ONCE: wreg[ks][nt], all indices compile-time ---
    const ushort* wbase = Wt + ((size_t)(w * 64 + lr)) * 32 + kg * 8;
    bf16x8 wreg[8][4];
#pragma unroll
    for (int ks = 0; ks < 8; ks++)
#pragma unroll
        for (int nt = 0; nt < 4; nt++)
            wreg[ks][nt] = *reinterpret_cast<const bf16x8*>(wbase + ks * 8192 + nt * 512);

    float bcol[4];
#pragma unroll
    for (int nt = 0; nt < 4; nt++) bcol[nt] = bias[w * 64 + nt * 16 + lr];

    float s1[4], s2[4];
#pragma unroll
    for (int nt = 0; nt < 4; nt++) { s1[nt] = 0.f; s2[nt] = 0.f; }

    for (int tile = blockIdx.x; tile < NTILES; tile += gridDim.x) {
        int row0 = tile * 32;
        const ushort* xbase = xbf + (size_t)row0 * HD;

        __syncthreads();  // previous tile's readers done before overwriting xs
#pragma unroll
        for (int i = 0; i < 4; i++) {
            int flat = i * 2048 + t * 8;
            i32x4 iv = *reinterpret_cast<const i32x4*>(xbase + flat);
            int row = flat >> 8;
            int k8 = (flat >> 3) & 31;
            int sw = k8 ^ (row & 7);
            *reinterpret_cast<i32x4*>(&xs[row * 256 + sw * 8]) = iv;
        }

        // prefetch this tile's residual rows: issued before the barrier, consumed after MFMAs
        float res[2][4][4];  // [mt][r][nt]
#pragma unroll
        for (int mt = 0; mt < 2; mt++)
#pragma unroll
            for (int r = 0; r < 4; r++) {
                size_t base = (size_t)(row0 + mt * 16 + kg * 4 + r) * HD;
#pragma unroll
                for (int nt = 0; nt < 4; nt++)
                    res[mt][r][nt] = hv[base + w * 64 + nt * 16 + lr];
            }

        __syncthreads();

        f32x4 acc[2][4];
#pragma unroll
        for (int m = 0; m < 2; m++)
#pragma unroll
            for (int n = 0; n < 4; n++) acc[m][n] = (f32x4){0.f, 0.f, 0.f, 0.f};

#define MFMASTEP(ks)                                                                             \
    {                                                                                            \
        int unit = (ks) * 4 + kg;                                                                \
        int rA0 = lr, rA1 = 16 + lr;                                                             \
        bf16x8 a0 = *reinterpret_cast<const bf16x8*>(&xs[rA0 * 256 + (unit ^ (rA0 & 7)) * 8]);   \
        bf16x8 a1 = *reinterpret_cast<const bf16x8*>(&xs[rA1 * 256 + (unit ^ (rA1 & 7)) * 8]);   \
        acc[0][0] = __builtin_amdgcn_mfma_f32_16x16x32_bf16(a0, wreg[ks][0], acc[0][0], 0, 0, 0);\
        acc[0][1] = __builtin_amdgcn_mfma_f32_16x16x32_bf16(a0, wreg[ks][1], acc[0][1], 0, 0, 0);\
        acc[0][2] = __builtin_amdgcn_mfma_f32_16x16x32_bf16(a0, wreg[ks][2], acc[0][2], 0, 0, 0);\
        acc[0][3] = __builtin_amdgcn_mfma_f32_16x16x32_bf16(a0, wreg[ks][3], acc[0][3], 0, 0, 0);\
        acc[1][0] = __builtin_amdgcn_mfma_f32_16x16x32_bf16(a1, wreg[ks][0], acc[1][0], 0, 0, 0);\
        acc[1][1] = __builtin_amdgcn_mfma_f32_16x16x32_bf16(a1, wreg[ks][1], acc[1][1], 0, 0, 0);\
        acc[1][2] = __builtin_amdgcn_mfma_f32_16x16x32_bf16(a1, wreg[ks][2], acc[1][2], 0, 0, 0);\
        acc[1][3] = __builtin_amdgcn_mfma_f32_16x16x32_bf16(a1, wreg[ks][3], acc[1][3], 0, 0, 0);\
    }
        MFMASTEP(0) MFMASTEP(1) MFMASTEP(2) MFMASTEP(3)
        MFMASTEP(4) MFMASTEP(5) MFMASTEP(6) MFMASTEP(7)
#undef MFMASTEP

        // epilogue: bias + prefetched residual + BN-stat accumulation
#pragma unroll
        for (int mt = 0; mt < 2; mt++) {
#pragma unroll
            for (int r = 0; r < 4; r++) {
                size_t base = (size_t)(row0 + mt * 16 + kg * 4 + r) * HD;
#pragma unroll
                for (int nt = 0; nt < 4; nt++) {
                    int col = w * 64 + nt * 16 + lr;
                    float v = acc[mt][nt][r] + bcol[nt] + res[mt][r][nt];
                    hv[base + col] = v;
                    s1[nt] += v;
                    s2[nt] += v * v;
                }
            }
        }
    }

    if (accum_stats) {
#pragma unroll
        for (int nt = 0; nt < 4; nt++) {
            s1[nt] += __shfl_xor(s1[nt], 16);
            s1[nt] += __shfl_xor(s1[nt], 32);
            s2[nt] += __shfl_xor(s2[nt], 16);
            s2[nt] += __shfl_xor(s2[nt], 32);
        }
        if (l < 16) {
            float* dst = part + (size_t)blockIdx.x * 512;
#pragma unroll
            for (int nt = 0; nt < 4; nt++) {
                int col = w * 64 + nt * 16 + l;
                dst[col] = s1[nt];
                dst[256 + col] = s2[nt];
            }
        }
    }
}

// ---------------- graph mean-pool ----------------
__global__ __launch_bounds__(256) void pool_kernel(const float* __restrict__ hv,
                                                   const int* __restrict__ gid,
                                                   float* __restrict__ hg,
                                                   float* __restrict__ cnt) {
    int c = threadIdx.x;
    int n0 = blockIdx.x * 32;
    int curg = gid[n0];
    float s = 0.f;
    int runlen = 0;
    for (int i = 0; i < 32; i++) {
        int n = n0 + i;
        int g = gid[n];
        if (g != curg) {
            atomicAdd(&hg[curg * HD + c], s);
            if (c == 0) atomicAdd(&cnt[curg], (float)runlen);
            curg = g;
            s = 0.f;
            runlen = 0;
        }
        s += hv[(size_t)n * HD + c];
        runlen++;
    }
    atomicAdd(&hg[curg * HD + c], s);
    if (c == 0) atomicAdd(&cnt[curg], (float)runlen);
}

// ---------------- final projection ----------------
__global__ __launch_bounds__(128) void out_kernel(const float* __restrict__ hg,
                                                  const float* __restrict__ cnt,
                                                  const float* __restrict__ wout,
                                                  const float* __restrict__ bout,
                                                  float* __restrict__ out) {
    __shared__ float hr[HD];
    int g = blockIdx.x, o = threadIdx.x;
    float inv = 1.0f / fmaxf(cnt[g], 1.0f);
    hr[o] = hg[g * HD + o] * inv;
    hr[o + 128] = hg[g * HD + o + 128] * inv;
    __syncthreads();
    float acc = bout[o];
#pragma unroll 4
    for (int k = 0; k < HD; k++) acc = fmaf(hr[k], wout[k * NOUT + o], acc);
    out[g * NOUT + o] = acc;
}

extern "C" void kernel_launch(void* const* d_in, const int* in_sizes, int n_in,
                              void* d_out, int out_size, void* d_ws, size_t ws_size,
                              hipStream_t stream) {
    const int* node_feats = (const int*)d_in[0];
    const int* edge_feats = (const int*)d_in[1];
    const int* src = (const int*)d_in[2];
    const int* dst = (const int*)d_in[3];
    const int* gid = (const int*)d_in[4];
    const float* atom_emb = (const float*)d_in[5];
    const float* bond_emb = (const float*)d_in[6];
    const float* gamma = (const float*)d_in[7];
    const float* beta = (const float*)d_in[8];
    const float* mlp_w = (const float*)d_in[9];
    const float* mlp_b = (const float*)d_in[10];
    const float* w_out = (const float*)d_in[11];
    const float* b_out = (const float*)d_in[12];
    float* out = (float*)d_out;

    float* ws = (float*)d_ws;
    float* hv = ws;                                       // [N][HD] f32
    ushort* h1 = (ushort*)(hv + (size_t)N_NODES * HD);    // [N][HD] bf16
    ushort* xbf = h1 + (size_t)N_NODES * HD;              // [N][HD] bf16
    ushort* Wt = xbf + (size_t)N_NODES * HD;              // [L][8][256][32] bf16 (k-slice-major)
    ushort* hetabs = Wt + (size_t)NLAYERS * HD * HD;      // [L][125][HD] bf16
    int* row_ptr = (int*)(hetabs + NLAYERS * 125 * HD);
    int* cursor = row_ptr + (N_NODES + 1);
    unsigned* pack_sorted = (unsigned*)(cursor + N_NODES);
    int* hist = (int*)(pack_sorted + N_EDGES);
    float* stats = (float*)(hist + N_NODES);              // [L][2][HD]
    float* hg = stats + NLAYERS * 2 * HD;                 // [G][HD]
    float* cnt = hg + NGRAPH * HD;                        // [G]
    float* part = cnt + NGRAPH;                           // [SP_BLOCKS][512] stat partials

    size_t zero_bytes = (size_t)(N_NODES + NLAYERS * 2 * HD + NGRAPH * HD + NGRAPH) * 4;
    hipMemsetAsync(hist, 0, zero_bytes, stream);

    hist_kernel<<<(N_EDGES + 255) / 256, 256, 0, stream>>>(dst, hist);
    scan_kernel<<<1, 1024, 0, stream>>>(hist, row_ptr, cursor);
    scatter_kernel<<<(N_EDGES + 255) / 256, 256, 0, stream>>>(dst, src, edge_feats, cursor,
                                                              pack_sorted);
    hetab_kernel<<<(NLAYERS * 125 * HD + 255) / 256, 256, 0, stream>>>(bond_emb, hetabs);
    wt_kernel<<<NLAYERS * HD, 256, 0, stream>>>(mlp_w, Wt);
    atom_kernel<<<N_NODES / 8, 256, 0, stream>>>(node_feats, atom_emb, hv);
    statsp_kernel<<<SP_BLOCKS, 256, 0, stream>>>(hv, part);
    statsred_kernel<<<64, 256, 0, stream>>>(part, stats, SP_BLOCKS);

    for (int l = 0; l < NLAYERS; l++) {
        bn_kernel<<<N_NODES * HD / 8 / 256, 256, 0, stream>>>(hv, stats + l * 2 * HD,
                                                              gamma + l * HD, beta + l * HD, h1);
        edge_kernel<<<N_NODES / 4, 256, 0, stream>>>(h1, xbf, row_ptr, pack_sorted,
                                                     hetabs + (size_t)l * 125 * HD);
        int acc_stats = (l < NLAYERS - 1) ? 1 : 0;
        mlp_mfma_kernel<<<512, 256, 0, stream>>>(xbf, hv, Wt + (size_t)l * 8 * 256 * 32,
                                                 mlp_b + l * HD, part, acc_stats);
        if (acc_stats)
            statsred_kernel<<<64, 256, 0, stream>>>(part, stats + (l + 1) * 2 * HD, 512);
    }

    pool_kernel<<<N_NODES / 32, 256, 0, stream>>>(hv, gid, hg, cnt);
    out_kernel<<<NGRAPH, 128, 0, stream>>>(hg, cnt, w_out, b_out, out);
}

// Round 21
// 490.693 us; speedup vs baseline: 1.0760x; 1.0760x over previous
//
#include <hip/hip_runtime.h>

#define N_NODES 20000
#define N_EDGES 320000
#define HD 256
#define NLAYERS 7
#define NGRAPH 512
#define NOUT 128
#define NTILES 625   // 20000 / 32
#define SP_BLOCKS 1024

typedef __attribute__((ext_vector_type(8))) short bf16x8;
typedef __attribute__((ext_vector_type(4))) int i32x4;
typedef __attribute__((ext_vector_type(4))) float f32x4;

__device__ __forceinline__ ushort f2bf(float f) {
    union { float f; unsigned u; } v;
    v.f = f;
    unsigned r = (v.u + 0x7FFFu + ((v.u >> 16) & 1u)) >> 16;
    return (ushort)r;
}
__device__ __forceinline__ float bf2f(ushort u) {
    union { unsigned u; float f; } v;
    v.u = (unsigned)u << 16;
    return v.f;
}
__device__ __forceinline__ float bflo(unsigned p) {
    union { unsigned u; float f; } v;
    v.u = p << 16;
    return v.f;
}
__device__ __forceinline__ float bfhi(unsigned p) {
    union { unsigned u; float f; } v;
    v.u = p & 0xffff0000u;
    return v.f;
}

// ---------------- CSR build ----------------
__global__ __launch_bounds__(256) void hist_kernel(const int* __restrict__ dst, int* __restrict__ hist) {
    int e = blockIdx.x * 256 + threadIdx.x;
    if (e < N_EDGES) atomicAdd(&hist[dst[e]], 1);
}

__global__ __launch_bounds__(1024) void scan_kernel(const int* __restrict__ hist,
                                                    int* __restrict__ row_ptr,
                                                    int* __restrict__ cursor) {
    __shared__ int sums[1024];
    int t = threadIdx.x;
    const int CH = 20;
    int base = t * CH;
    int local[20];
    int s = 0;
#pragma unroll
    for (int i = 0; i < CH; i++) {
        int v = (base + i < N_NODES) ? hist[base + i] : 0;
        local[i] = s;
        s += v;
    }
    sums[t] = s;
    __syncthreads();
    for (int off = 1; off < 1024; off <<= 1) {
        int v = (t >= off) ? sums[t - off] : 0;
        __syncthreads();
        sums[t] += v;
        __syncthreads();
    }
    int offset = (t == 0) ? 0 : sums[t - 1];
#pragma unroll
    for (int i = 0; i < CH; i++) {
        int idx = base + i;
        if (idx < N_NODES) {
            int v = offset + local[i];
            row_ptr[idx] = v;
            cursor[idx] = v;
        }
    }
    if (t == 1023) row_ptr[N_NODES] = sums[1023];
}

// pack = src | (combo << 15)   (src < 32768, combo < 125)
__global__ __launch_bounds__(256) void scatter_kernel(const int* __restrict__ dst,
                                                      const int* __restrict__ src,
                                                      const int* __restrict__ ef,
                                                      int* __restrict__ cursor,
                                                      unsigned* __restrict__ pack_sorted) {
    int e = blockIdx.x * 256 + threadIdx.x;
    if (e < N_EDGES) {
        int d = dst[e];
        int p = atomicAdd(&cursor[d], 1);
        unsigned cb = (unsigned)(ef[e * 3] * 25 + ef[e * 3 + 1] * 5 + ef[e * 3 + 2]);
        pack_sorted[p] = (unsigned)src[e] | (cb << 15);
    }
}

// ---------------- bond-embedding combo tables (bf16): [L][125][H] ----------------
__global__ __launch_bounds__(256) void hetab_kernel(const float* __restrict__ bond,
                                                    ushort* __restrict__ he) {
    int idx = blockIdx.x * 256 + threadIdx.x;
    if (idx >= NLAYERS * 125 * HD) return;
    int h = idx & (HD - 1);
    int rem = idx >> 8;
    int l = rem / 125;
    int c = rem - l * 125;
    int f0 = c / 25, f1 = (c / 5) % 5, f2 = c % 5;
    const float* b = bond + (size_t)l * 3 * 8 * HD;
    he[idx] = f2bf(b[(0 * 8 + f0) * HD + h] + b[(1 * 8 + f1) * HD + h] + b[(2 * 8 + f2) * HD + h]);
}

// ---- W -> Wt2 bf16, k-slice-major: Wt2[l][ks][n][kg][8], ks=k>>5, kg=(k>>3)&3, j=k&7 ----
__global__ __launch_bounds__(256) void wt_kernel(const float* __restrict__ W,
                                                 ushort* __restrict__ Wt) {
    int b = blockIdx.x;
    int l = b >> 8;
    int n = b & 255;
    int k = threadIdx.x;
    float v = W[((size_t)l * HD + k) * HD + n];
    int ks = k >> 5, kg = (k >> 3) & 3, j = k & 7;
    Wt[(((size_t)l * 8 + ks) * 256 + n) * 32 + kg * 8 + j] = f2bf(v);
}

// ------- atom encoder: 8 nodes/block, NO atomics (stats decoupled) ----------
__global__ __launch_bounds__(256) void atom_kernel(const int* __restrict__ nf,
                                                   const float* __restrict__ emb,
                                                   float* __restrict__ hv) {
    int c = threadIdx.x;
    int n0 = blockIdx.x * 8;
#pragma unroll
    for (int i = 0; i < 8; i++) {
        int n = n0 + i;
        const int* f = nf + n * 9;
        float v = 0.f;
#pragma unroll
        for (int j = 0; j < 9; j++) v += emb[(j * 128 + f[j]) * HD + c];
        hv[(size_t)n * HD + c] = v;
    }
}

// ------- layer-0 BN stat partials: 1024 blocks, NO atomics ----------
__global__ __launch_bounds__(256) void statsp_kernel(const float* __restrict__ hv,
                                                     float* __restrict__ part) {
    int c = threadIdx.x;
    float s1 = 0.f, s2 = 0.f;
    for (int n = blockIdx.x; n < N_NODES; n += SP_BLOCKS) {
        float v = hv[(size_t)n * HD + c];
        s1 += v;
        s2 += v * v;
    }
    float* dst = part + (size_t)blockIdx.x * 512;
    dst[c] = s1;
    dst[256 + c] = s2;
}

// ------- reduce per-block partials -> stats (spread atomics) ----------
__global__ __launch_bounds__(256) void statsred_kernel(const float* __restrict__ part,
                                                       float* __restrict__ stats,
                                                       int nblocks) {
    int c = threadIdx.x;
    float a0 = 0.f, a1 = 0.f;
    for (int b = blockIdx.x; b < nblocks; b += gridDim.x) {
        a0 += part[(size_t)b * 512 + c];
        a1 += part[(size_t)b * 512 + 256 + c];
    }
    atomicAdd(&stats[c], a0);
    atomicAdd(&stats[HD + c], a1);
}

// ---------------- BN+ReLU -> bf16 h1 ----------------
__global__ __launch_bounds__(256) void bn_kernel(const float* __restrict__ hv,
                                                 const float* __restrict__ stats,
                                                 const float* __restrict__ gamma,
                                                 const float* __restrict__ beta,
                                                 ushort* __restrict__ h1) {
    int tid = blockIdx.x * 256 + threadIdx.x;  // N*HD/8 threads
    int idx = tid * 8;
    int c = idx & (HD - 1);
    float4 f0 = *reinterpret_cast<const float4*>(hv + idx);
    float4 f1 = *reinterpret_cast<const float4*>(hv + idx + 4);
    float v[8] = {f0.x, f0.y, f0.z, f0.w, f1.x, f1.y, f1.z, f1.w};
    ushort o[8];
#pragma unroll
    for (int j = 0; j < 8; j++) {
        float mu = stats[c + j] * (1.0f / N_NODES);
        float var = stats[HD + c + j] * (1.0f / N_NODES) - mu * mu;
        float a = gamma[c + j] * rsqrtf(fmaxf(var, 0.f) + 1e-5f);
        float b = beta[c + j] - mu * a;
        o[j] = f2bf(fmaxf(fmaf(v[j], a, b), 0.f));
    }
    i32x4 pack;
    pack.x = (int)o[0] | ((int)o[1] << 16);
    pack.y = (int)o[2] | ((int)o[3] << 16);
    pack.z = (int)o[4] | ((int)o[5] << 16);
    pack.w = (int)o[6] | ((int)o[7] << 16);
    *reinterpret_cast<i32x4*>(h1 + idx) = pack;
}

// ---------------- edge pass (R9 winner): wave/node, 4ch/lane, 64-edge preload, 4-deep ----
__global__ __launch_bounds__(256) void edge_kernel(const ushort* __restrict__ h1,
                                                   ushort* __restrict__ xbf,
                                                   const int* __restrict__ row_ptr,
                                                   const unsigned* __restrict__ pack_sorted,
                                                   const ushort* __restrict__ hetab) {
    int wv = threadIdx.x >> 6;
    int lane = threadIdx.x & 63;
    int n = blockIdx.x * 4 + wv;
    int c4 = lane * 4;
    int e0 = row_ptr[n];
    int deg = row_ptr[n + 1] - e0;

    float S0 = 0.f, S1 = 0.f, S2 = 0.f, S3 = 0.f;
    float T0 = 0.f, T1 = 0.f, T2 = 0.f, T3 = 0.f;

#define GATHER(i, P)                                                                          \
    uint2 hs##i = *reinterpret_cast<const uint2*>(h1 + ((size_t)((P) & 0x7FFFu) << 8) + c4);  \
    uint2 hb##i = *reinterpret_cast<const uint2*>(hetab + (((P) >> 15) << 8) + c4);

#define EDGE_PROC(HS, HB)                                                  \
    {                                                                      \
        float m0 = fmaxf(bflo(HS.x) + bflo(HB.x), 0.f);                    \
        float m1 = fmaxf(bfhi(HS.x) + bfhi(HB.x), 0.f);                    \
        float m2 = fmaxf(bflo(HS.y) + bflo(HB.y), 0.f);                    \
        float m3 = fmaxf(bfhi(HS.y) + bfhi(HB.y), 0.f);                    \
        float x0 = __expf(m0), x1 = __expf(m1), x2 = __expf(m2), x3 = __expf(m3); \
        S0 += x0; T0 = fmaf(m0, x0, T0);                                   \
        S1 += x1; T1 = fmaf(m1, x1, T1);                                   \
        S2 += x2; T2 = fmaf(m2, x2, T2);                                   \
        S3 += x3; T3 = fmaf(m3, x3, T3);                                   \
    }

    for (int base = 0; base < deg; base += 64) {
        int cnt = min(64, deg - base);
        unsigned pk = (lane < cnt) ? pack_sorted[e0 + base + lane] : 0u;
        int j = 0;
        for (; j + 4 <= cnt; j += 4) {
            unsigned p0 = __shfl(pk, j + 0);
            unsigned p1 = __shfl(pk, j + 1);
            unsigned p2 = __shfl(pk, j + 2);
            unsigned p3 = __shfl(pk, j + 3);
            GATHER(0, p0) GATHER(1, p1) GATHER(2, p2) GATHER(3, p3)
            EDGE_PROC(hs0, hb0) EDGE_PROC(hs1, hb1) EDGE_PROC(hs2, hb2) EDGE_PROC(hs3, hb3)
        }
        for (; j < cnt; j++) {
            unsigned p0 = __shfl(pk, j);
            GATHER(0, p0)
            EDGE_PROC(hs0, hb0)
        }
    }
#undef EDGE_PROC
#undef GATHER

    // softmax weights shift-invariant in the +1e-7; m linear in it -> add at end
    float a0 = (S0 > 0.f) ? (T0 / S0 + 1e-7f) : 0.f;
    float a1 = (S1 > 0.f) ? (T1 / S1 + 1e-7f) : 0.f;
    float a2 = (S2 > 0.f) ? (T2 / S2 + 1e-7f) : 0.f;
    float a3 = (S3 > 0.f) ? (T3 / S3 + 1e-7f) : 0.f;

    uint2 ho = *reinterpret_cast<const uint2*>(h1 + ((size_t)n << 8) + c4);
    unsigned o0 = f2bf(bflo(ho.x) + a0);
    unsigned o1 = f2bf(bfhi(ho.x) + a1);
    unsigned o2 = f2bf(bflo(ho.y) + a2);
    unsigned o3 = f2bf(bfhi(ho.y) + a3);
    uint2 res;
    res.x = o0 | (o1 << 16);
    res.y = o2 | (o3 << 16);
    *reinterpret_cast<uint2*>(xbf + ((size_t)n << 8) + c4) = res;
}

// ------- MFMA MLP, persistent tiles: W in regs; residual prefetched; partials, no atomics --
__global__ __launch_bounds__(256, 2) void mlp_mfma_kernel(const ushort* __restrict__ xbf,
                                                          float* __restrict__ hv,
                                                          const ushort* __restrict__ Wt,
                                                          const float* __restrict__ bias,
                                                          float* __restrict__ part,
                                                          int accum_stats) {
    __shared__ __attribute__((aligned(16))) ushort xs[32 * 256];  // bf16, XOR-swizzled 16B units

    int t = threadIdx.x;
    int l = t & 63;
    int w = t >> 6;
    int kg = l >> 4;         // k-group 0..3
    int lr = l & 15;         // row (A) / col (B/D) within tile

    // --- load this wave's W columns ONCE: wreg[ks][nt], all indices compile-time ---
    const ushort* wbase = Wt + ((size_t)(w * 64 + lr)) * 32 + kg * 8;
    bf16x8 wreg[8][4];
#pragma unroll
    for (int ks = 0; ks < 8; ks++)
#pragma unroll
        for (int nt = 0; nt < 4; nt++)
            wreg[ks][nt] = *reinterpret_cast<const bf16x8*>(wbase + ks * 8192 + nt * 512);

    float bcol[4];
#pragma unroll
    for (int nt = 0; nt < 4; nt++) bcol[nt] = bias[w * 64 + nt * 16 + lr];

    float s1[4], s2[4];
#pragma unroll
    for (int nt = 0; nt < 4; nt++) { s1[nt] = 0.f; s2[nt] = 0.f; }

    for (int tile = blockIdx.x; tile < NTILES; tile += gridDim.x) {
        int row0 = tile * 32;
        const ushort* xbase = xbf + (size_t)row0 * HD;

        __syncthreads();  // previous tile's readers done before overwriting xs
#pragma unroll
        for (int i = 0; i < 4; i++) {
            int flat = i * 2048 + t * 8;
            i32x4 iv = *reinterpret_cast<const i32x4*>(xbase + flat);
            int row = flat >> 8;
            int k8 = (flat >> 3) & 31;
            int sw = k8 ^ (row & 7);
            *reinterpret_cast<i32x4*>(&xs[row * 256 + sw * 8]) = iv;
        }

        // prefetch this tile's residual rows: issued before the barrier, consumed after MFMAs
        float res[2][4][4];  // [mt][r][nt]
#pragma unroll
        for (int mt = 0; mt < 2; mt++)
#pragma unroll
            for (int r = 0; r < 4; r++) {
                size_t base = (size_t)(row0 + mt * 16 + kg * 4 + r) * HD;
#pragma unroll
                for (int nt = 0; nt < 4; nt++)
                    res[mt][r][nt] = hv[base + w * 64 + nt * 16 + lr];
            }

        __syncthreads();

        f32x4 acc[2][4];
#pragma unroll
        for (int m = 0; m < 2; m++)
#pragma unroll
            for (int n = 0; n < 4; n++) acc[m][n] = (f32x4){0.f, 0.f, 0.f, 0.f};

#define MFMASTEP(ks)                                                                             \
    {                                                                                            \
        int unit = (ks) * 4 + kg;                                                                \
        int rA0 = lr, rA1 = 16 + lr;                                                             \
        bf16x8 a0 = *reinterpret_cast<const bf16x8*>(&xs[rA0 * 256 + (unit ^ (rA0 & 7)) * 8]);   \
        bf16x8 a1 = *reinterpret_cast<const bf16x8*>(&xs[rA1 * 256 + (unit ^ (rA1 & 7)) * 8]);   \
        acc[0][0] = __builtin_amdgcn_mfma_f32_16x16x32_bf16(a0, wreg[ks][0], acc[0][0], 0, 0, 0);\
        acc[0][1] = __builtin_amdgcn_mfma_f32_16x16x32_bf16(a0, wreg[ks][1], acc[0][1], 0, 0, 0);\
        acc[0][2] = __builtin_amdgcn_mfma_f32_16x16x32_bf16(a0, wreg[ks][2], acc[0][2], 0, 0, 0);\
        acc[0][3] = __builtin_amdgcn_mfma_f32_16x16x32_bf16(a0, wreg[ks][3], acc[0][3], 0, 0, 0);\
        acc[1][0] = __builtin_amdgcn_mfma_f32_16x16x32_bf16(a1, wreg[ks][0], acc[1][0], 0, 0, 0);\
        acc[1][1] = __builtin_amdgcn_mfma_f32_16x16x32_bf16(a1, wreg[ks][1], acc[1][1], 0, 0, 0);\
        acc[1][2] = __builtin_amdgcn_mfma_f32_16x16x32_bf16(a1, wreg[ks][2], acc[1][2], 0, 0, 0);\
        acc[1][3] = __builtin_amdgcn_mfma_f32_16x16x32_bf16(a1, wreg[ks][3], acc[1][3], 0, 0, 0);\
    }
        MFMASTEP(0) MFMASTEP(1) MFMASTEP(2) MFMASTEP(3)
        MFMASTEP(4) MFMASTEP(5) MFMASTEP(6) MFMASTEP(7)
#undef MFMASTEP

        // epilogue: bias + prefetched residual + BN-stat accumulation
#pragma unroll
        for (int mt = 0; mt < 2; mt++) {
#pragma unroll
            for (int r = 0; r < 4; r++) {
                size_t base = (size_t)(row0 + mt * 16 + kg * 4 + r) * HD;
#pragma unroll
                for (int nt = 0; nt < 4; nt++) {
                    int col = w * 64 + nt * 16 + lr;
                    float v = acc[mt][nt][r] + bcol[nt] + res[mt][r][nt];
                    hv[base + col] = v;
                    s1[nt] += v;
                    s2[nt] += v * v;
                }
            }
        }
    }

    if (accum_stats) {
#pragma unroll
        for (int nt = 0; nt < 4; nt++) {
            s1[nt] += __shfl_xor(s1[nt], 16);
            s1[nt] += __shfl_xor(s1[nt], 32);
            s2[nt] += __shfl_xor(s2[nt], 16);
            s2[nt] += __shfl_xor(s2[nt], 32);
        }
        if (l < 16) {
            float* dst = part + (size_t)blockIdx.x * 512;
#pragma unroll
            for (int nt = 0; nt < 4; nt++) {
                int col = w * 64 + nt * 16 + l;
                dst[col] = s1[nt];
                dst[256 + col] = s2[nt];
            }
        }
    }
}

// ---------------- graph mean-pool ----------------
__global__ __launch_bounds__(256) void pool_kernel(const float* __restrict__ hv,
                                                   const int* __restrict__ gid,
                                                   float* __restrict__ hg,
                                                   float* __restrict__ cnt) {
    int c = threadIdx.x;
    int n0 = blockIdx.x * 32;
    int curg = gid[n0];
    float s = 0.f;
    int runlen = 0;
    for (int i = 0; i < 32; i++) {
        int n = n0 + i;
        int g = gid[n];
        if (g != curg) {
            atomicAdd(&hg[curg * HD + c], s);
            if (c == 0) atomicAdd(&cnt[curg], (float)runlen);
            curg = g;
            s = 0.f;
            runlen = 0;
        }
        s += hv[(size_t)n * HD + c];
        runlen++;
    }
    atomicAdd(&hg[curg * HD + c], s);
    if (c == 0) atomicAdd(&cnt[curg], (float)runlen);
}

// ---------------- final projection ----------------
__global__ __launch_bounds__(128) void out_kernel(const float* __restrict__ hg,
                                                  const float* __restrict__ cnt,
                                                  const float* __restrict__ wout,
                                                  const float* __restrict__ bout,
                                                  float* __restrict__ out) {
    __shared__ float hr[HD];
    int g = blockIdx.x, o = threadIdx.x;
    float inv = 1.0f / fmaxf(cnt[g], 1.0f);
    hr[o] = hg[g * HD + o] * inv;
    hr[o + 128] = hg[g * HD + o + 128] * inv;
    __syncthreads();
    float acc = bout[o];
#pragma unroll 4
    for (int k = 0; k < HD; k++) acc = fmaf(hr[k], wout[k * NOUT + o], acc);
    out[g * NOUT + o] = acc;
}

extern "C" void kernel_launch(void* const* d_in, const int* in_sizes, int n_in,
                              void* d_out, int out_size, void* d_ws, size_t ws_size,
                              hipStream_t stream) {
    const int* node_feats = (const int*)d_in[0];
    const int* edge_feats = (const int*)d_in[1];
    const int* src = (const int*)d_in[2];
    const int* dst = (const int*)d_in[3];
    const int* gid = (const int*)d_in[4];
    const float* atom_emb = (const float*)d_in[5];
    const float* bond_emb = (const float*)d_in[6];
    const float* gamma = (const float*)d_in[7];
    const float* beta = (const float*)d_in[8];
    const float* mlp_w = (const float*)d_in[9];
    const float* mlp_b = (const float*)d_in[10];
    const float* w_out = (const float*)d_in[11];
    const float* b_out = (const float*)d_in[12];
    float* out = (float*)d_out;

    float* ws = (float*)d_ws;
    float* hv = ws;                                       // [N][HD] f32
    ushort* h1 = (ushort*)(hv + (size_t)N_NODES * HD);    // [N][HD] bf16
    ushort* xbf = h1 + (size_t)N_NODES * HD;              // [N][HD] bf16
    ushort* Wt = xbf + (size_t)N_NODES * HD;              // [L][8][256][32] bf16 (k-slice-major)
    ushort* hetabs = Wt + (size_t)NLAYERS * HD * HD;      // [L][125][HD] bf16
    int* row_ptr = (int*)(hetabs + NLAYERS * 125 * HD);
    int* cursor = row_ptr + (N_NODES + 1);
    unsigned* pack_sorted = (unsigned*)(cursor + N_NODES);
    int* hist = (int*)(pack_sorted + N_EDGES);
    float* stats = (float*)(hist + N_NODES);              // [L][2][HD]
    float* hg = stats + NLAYERS * 2 * HD;                 // [G][HD]
    float* cnt = hg + NGRAPH * HD;                        // [G]
    float* part = cnt + NGRAPH;                           // [SP_BLOCKS][512] stat partials

    size_t zero_bytes = (size_t)(N_NODES + NLAYERS * 2 * HD + NGRAPH * HD + NGRAPH) * 4;
    hipMemsetAsync(hist, 0, zero_bytes, stream);

    hist_kernel<<<(N_EDGES + 255) / 256, 256, 0, stream>>>(dst, hist);
    scan_kernel<<<1, 1024, 0, stream>>>(hist, row_ptr, cursor);
    scatter_kernel<<<(N_EDGES + 255) / 256, 256, 0, stream>>>(dst, src, edge_feats, cursor,
                                                              pack_sorted);
    hetab_kernel<<<(NLAYERS * 125 * HD + 255) / 256, 256, 0, stream>>>(bond_emb, hetabs);
    wt_kernel<<<NLAYERS * HD, 256, 0, stream>>>(mlp_w, Wt);
    atom_kernel<<<N_NODES / 8, 256, 0, stream>>>(node_feats, atom_emb, hv);
    statsp_kernel<<<SP_BLOCKS, 256, 0, stream>>>(hv, part);
    statsred_kernel<<<64, 256, 0, stream>>>(part, stats, SP_BLOCKS);

    for (int l = 0; l < NLAYERS; l++) {
        bn_kernel<<<N_NODES * HD / 8 / 256, 256, 0, stream>>>(hv, stats + l * 2 * HD,
                                                              gamma + l * HD, beta + l * HD, h1);
        edge_kernel<<<N_NODES / 4, 256, 0, stream>>>(h1, xbf, row_ptr, pack_sorted,
                                                     hetabs + (size_t)l * 125 * HD);
        int acc_stats = (l < NLAYERS - 1) ? 1 : 0;
        mlp_mfma_kernel<<<512, 256, 0, stream>>>(xbf, hv, Wt + (size_t)l * 8 * 256 * 32,
                                                 mlp_b + l * HD, part, acc_stats);
        if (acc_stats)
            statsred_kernel<<<64, 256, 0, stream>>>(part, stats + (l + 1) * 2 * HD, 512);
    }

    pool_kernel<<<N_NODES / 32, 256, 0, stream>>>(hv, gid, hg, cnt);
    out_kernel<<<NGRAPH, 128, 0, stream>>>(hg, cnt, w_out, b_out, out);
}